// Round 17
// baseline (157.206 us; speedup 1.0000x reference)
//
#include <hip/hip_runtime.h>

#define T_STEPS 512
#define BATCH 64

// fp32 casts of np.exp(-1/20), np.exp(-1/5)
__device__ constexpr float ALPHA_ = 0.95122942450071400910f;
__device__ constexpr float BETA_  = 0.81873075307798185867f;

typedef __attribute__((ext_vector_type(8))) short bf16x8;
typedef __attribute__((ext_vector_type(4))) float f32x4;

__device__ inline unsigned short f2bf_rne(float f) {
  union { float f; unsigned int u; } v{f};
  const unsigned int u = v.u;
  return (unsigned short)((u + 0x7FFFu + ((u >> 16) & 1u)) >> 16);
}
__device__ inline float bf2f(unsigned short h) {
  union { unsigned int u; float f; } v{(unsigned int)h << 16};
  return v.f;
}

__device__ inline void gload16(const void* g, void* l) {
  __builtin_amdgcn_global_load_lds(
      (const __attribute__((address_space(1))) unsigned int*)g,
      (__attribute__((address_space(3))) unsigned int*)l, 16, 0, 0);
}

// pack trunc-bf16(first) | trunc-bf16(second)<<16  (exact for spike 0/1)
__device__ inline unsigned int pkbf(float first, float second) {
#if __has_builtin(__builtin_amdgcn_perm)
  return __builtin_amdgcn_perm(__float_as_uint(second), __float_as_uint(first),
                               0x07060302u);
#else
  return (__float_as_uint(first) >> 16) | (__float_as_uint(second) & 0xFFFF0000u);
#endif
}

// 8 fp32 (lo = k0..3, hi = k4..7) -> MFMA bf16x8 fragment word order
__device__ inline bf16x8 cvt_frag(const f32x4 lo, const f32x4 hi) {
  union { unsigned int w[4]; bf16x8 v; } u;
  u.w[0] = pkbf(lo.x, lo.y);
  u.w[1] = pkbf(lo.z, lo.w);
  u.w[2] = pkbf(hi.x, hi.y);
  u.w[3] = pkbf(hi.z, hi.w);
  return u.v;
}

#define SB __builtin_amdgcn_sched_barrier(0)

// ---------------------------------------------------------------------------
// GEMM0 kernel, BK=64 (HALF the K-steps of all prior rounds — tests the
// fixed-per-step-cost hypothesis: every structure at BK=32 paid wait+barrier+
// issue overhead x32; this pays it x16 with dense 32-MFMA/wave steps).
//   BM=64 (WM=2,TM=32), BN=128 (WC=2), 256 thr, grid (2,512), LDS 48 KB.
//   A fp32: COAL staging — 16 KB/step as [64 rows][256 B] rows, contiguous
//   256 B per row per step, chunk-XOR swizzle ((r&7)<<4) on source AND
//   ds_read (2-way banks, free). Triple-buffered, depth-2 prefetch.
//   B: frag-linear hi/lo bf16, 2 k-subtiles/step, ping-pong register sets
//   (compiler-managed waits). Counted s_waitcnt vmcnt(AIP+32)=vmcnt(36)
//   before the raw s_barrier: outstanding = [A(kb+1) 4][B(kb+1) 16]
//   [A(kb+2) 4][B(kb+2) 16] -> completes exactly A(kb+1).
//   K-order per acc element: kb32 ascending — bit-identical to BK=32 rounds.
// ---------------------------------------------------------------------------
__global__ __launch_bounds__(256, 2) void gemm_bk64(
    const float* __restrict__ A, const char* __restrict__ Bhi,
    const char* __restrict__ Blo, const float* __restrict__ cvec,
    float* __restrict__ C, int N, int K) {
  constexpr int AIP = 4;          // A gloads per thread per step (16 KB/256/16)
  constexpr int W2N = AIP + 32;   // completes A(next)
  __shared__ char smem[3 * 16384];

  const int tid = threadIdx.x;
  const int lane = tid & 63;
  const int wave = tid >> 6;
  const int wm = wave >> 1, wc = wave & 1;
  const int l15 = lane & 15, l4 = lane >> 4;
  const int row0 = blockIdx.y * 64;
  const int col0 = blockIdx.x * 128;
  const int KB32 = K / 32;
  const int KB64 = K / 64;

  const char* Ab = (const char*)A;
  // A staging: unit u = i*256+tid in [0,1024): row r=u>>4, chunk c=u&15.
  // Source k-byte = (c*16) ^ ((r&7)<<4); LDS dest = u*16 (linear).
  const char* a_src[AIP];
#pragma unroll
  for (int i = 0; i < AIP; ++i) {
    const int unit = i * 256 + tid;
    const int r = unit >> 4, c = unit & 15;
    a_src[i] = Ab + ((size_t)(row0 + r) * K) * 4 + ((c * 16) ^ ((r & 7) << 4));
  }
  const char* bh_base = Bhi + (size_t)(blockIdx.x * 2 + wc) * KB32 * 4096 + (size_t)lane * 16;
  const char* bl_base = Blo + (size_t)(blockIdx.x * 2 + wc) * KB32 * 4096 + (size_t)lane * 16;

  int aoff = 0, boff = 0;
  const int amax = (KB64 - 1) * 256;
  const int bmax = (KB64 - 1) * 8192;

  f32x4 acc[2][4] = {};
  bf16x8 bh0[8], bl0[8], bh1[8], bl1[8];   // [ks*4+n], two ping-pong sets

#define STAGE_A(buf)                                                   \
  do {                                                                 \
    _Pragma("unroll") for (int i = 0; i < AIP; ++i)                    \
        gload16(a_src[i] + aoff, (buf) + (i * 256 + tid) * 16);        \
  } while (0)

#define LOAD_B(bh, bl, off_)                                           \
  do {                                                                 \
    _Pragma("unroll") for (int ks = 0; ks < 2; ++ks) {                 \
      const char* ph = bh_base + (off_) + ks * 4096;                   \
      const char* pl = bl_base + (off_) + ks * 4096;                   \
      _Pragma("unroll") for (int n = 0; n < 4; ++n) {                  \
        bh[ks * 4 + n] = *(const bf16x8*)(ph + n * 1024);              \
        bl[ks * 4 + n] = *(const bf16x8*)(pl + n * 1024);              \
      }                                                                \
    }                                                                  \
  } while (0)

  char* bufR = smem;
  char* bufM = smem + 16384;
  char* bufS = smem + 32768;

  // ---- prologue ----
  SB;
  STAGE_A(bufR);                      // A(0)
  SB;
  LOAD_B(bh0, bl0, 0);                // B(0)
  SB;
  aoff = 256;
  STAGE_A(bufM);                      // A(1)
  SB;
  LOAD_B(bh1, bl1, 8192);             // B(1)   (KB64 = 16 >= 4)
  SB;
  aoff = (512 < amax) ? 512 : amax;
  boff = (16384 < bmax) ? 16384 : bmax;
  asm volatile("s_waitcnt vmcnt(%0)" ::"i"(W2N) : "memory");  // A(0) landed
  __builtin_amdgcn_s_barrier();
  SB;

#define KSTEP(BH, BL)                                                        \
  do {                                                                       \
    STAGE_A(bufS); /* A(kb+2) */                                             \
    aoff = (aoff < amax) ? aoff + 256 : aoff;                                \
    SB;                                                                      \
    bf16x8 af[2][2];                                                         \
    _Pragma("unroll") for (int m = 0; m < 2; ++m) {                          \
      const int rr = wm * 32 + m * 16 + l15;                                 \
      const int sw = (rr & 7) << 4;                                          \
      _Pragma("unroll") for (int ks = 0; ks < 2; ++ks) {                     \
        const int off = ks * 128 + l4 * 32;                                  \
        const f32x4 lo = *(const f32x4*)(bufR + rr * 256 + (off ^ sw));      \
        const f32x4 hi = *(const f32x4*)(bufR + rr * 256 + ((off + 16) ^ sw)); \
        af[ks][m] = cvt_frag(lo, hi);                                        \
      }                                                                      \
    }                                                                        \
    SB;                                                                      \
    _Pragma("unroll") for (int ks = 0; ks < 2; ++ks)                         \
      _Pragma("unroll") for (int m = 0; m < 2; ++m)                          \
        _Pragma("unroll") for (int n = 0; n < 4; ++n) {                      \
          acc[m][n] = __builtin_amdgcn_mfma_f32_16x16x32_bf16(                \
              af[ks][m], BH[ks * 4 + n], acc[m][n], 0, 0, 0);                \
          acc[m][n] = __builtin_amdgcn_mfma_f32_16x16x32_bf16(                \
              af[ks][m], BL[ks * 4 + n], acc[m][n], 0, 0, 0);                \
        }                                                                    \
    SB;                                                                      \
    LOAD_B(BH, BL, boff); /* B(kb+2) */                                      \
    boff = (boff < bmax) ? boff + 8192 : boff;                               \
    SB;                                                                      \
    asm volatile("s_waitcnt vmcnt(%0)" ::"i"(W2N) : "memory");               \
    __builtin_amdgcn_s_barrier();                                            \
    SB;                                                                      \
    { char* t = bufR; bufR = bufM; bufM = bufS; bufS = t; }                  \
  } while (0)

  const int ITER = KB64 / 2;   // 8 (K runtime -> not fully unrolled)
  for (int it = 0; it < ITER; ++it) {
    KSTEP(bh0, bl0);
    KSTEP(bh1, bl1);
  }
  asm volatile("s_waitcnt vmcnt(0) lgkmcnt(0)" ::: "memory");

#undef KSTEP
#undef LOAD_B
#undef STAGE_A

  // ---- epilogue ----
#pragma unroll
  for (int m = 0; m < 2; ++m) {
    const int rbase = row0 + wm * 32 + m * 16 + l4 * 4;
#pragma unroll
    for (int n = 0; n < 4; ++n) {
      const int c = col0 + wc * 64 + n * 16 + l15;
      const float cc = cvec[c];
#pragma unroll
      for (int r = 0; r < 4; ++r)
        C[(size_t)(rbase + r) * N + c] = acc[m][n][r] + cc;
    }
  }
}

// ---------------------------------------------------------------------------
// R8/R15 deep-pipelined GEMM (layers 1-2, 256 threads). Depth-2 prefetch,
// triple-buffer A LDS via gload_lds, B in compiler-managed ping-pong regs,
// counted vmcnt(AIP+16) before the raw s_barrier completes exactly A(next).
// ---------------------------------------------------------------------------
template <int WM, int WC, int TM, bool LNFOLD>
__global__ __launch_bounds__(256) void gemm_deep2(
    const void* __restrict__ Av, const char* __restrict__ Bhi,
    const char* __restrict__ Blo, const float* __restrict__ uvec,
    const float* __restrict__ cvec, float* __restrict__ C, int N, int K) {
  constexpr int BM = WM * TM;
  constexpr int FM = TM / 16;          // m-frags per wave
  constexpr int ABY = BM * 64;         // A bytes per K-step (bf16)
  constexpr int AIP = ABY / 4096;      // A gloads per thread
  constexpr int ASTEP = 64;            // A source bytes per kb
  constexpr int W2N = AIP + 16;        // completes A(next)
  __shared__ char smem[3 * ABY];

  const int tid = threadIdx.x;
  const int lane = tid & 63;
  const int wave = tid >> 6;
  const int wm = wave / WC, wc = wave % WC;
  const int l15 = lane & 15, l4 = lane >> 4;
  const int row0 = blockIdx.y * BM;
  const int col0 = blockIdx.x * (WC * 64);
  const int KB = K / 32;

  const char* Ab = (const char*)Av;

  const char* a_src[AIP];
#pragma unroll
  for (int i = 0; i < AIP; ++i) {
    const int unit = i * 256 + tid;
    const int r = ((unit >> 6) << 4) | (unit & 15);
    const int j = (unit >> 4) & 3;
    a_src[i] = Ab + ((size_t)(row0 + r) * K + j * 8) * 2;
  }
  const char* bh_base = Bhi + (size_t)(blockIdx.x * WC + wc) * KB * 4096 + (size_t)lane * 16;
  const char* bl_base = Blo + (size_t)(blockIdx.x * WC + wc) * KB * 4096 + (size_t)lane * 16;

  int aoff = 0, boff = 0;
  const int amax = (KB - 1) * ASTEP;
  const int bmax = (KB - 1) * 4096;

  f32x4 acc[FM][4] = {};
  f32x4 acc1[FM] = {};
  const bf16x8 ONES = {0x3F80, 0x3F80, 0x3F80, 0x3F80,
                       0x3F80, 0x3F80, 0x3F80, 0x3F80};
  bf16x8 bh0[4], bl0[4], bh1[4], bl1[4];

#define STAGE_A(buf)                                                   \
  do {                                                                 \
    _Pragma("unroll") for (int i = 0; i < AIP; ++i)                    \
        gload16(a_src[i] + aoff, (buf) + (i * 256 + tid) * 16);        \
  } while (0)

#define LOAD_B(bh, bl, off_)                                           \
  do {                                                                 \
    const char* ph = bh_base + (off_);                                 \
    const char* pl = bl_base + (off_);                                 \
    bh[0] = *(const bf16x8*)(ph);                                      \
    bh[1] = *(const bf16x8*)(ph + 1024);                               \
    bh[2] = *(const bf16x8*)(ph + 2048);                               \
    bh[3] = *(const bf16x8*)(ph + 3072);                               \
    bl[0] = *(const bf16x8*)(pl);                                      \
    bl[1] = *(const bf16x8*)(pl + 1024);                               \
    bl[2] = *(const bf16x8*)(pl + 2048);                               \
    bl[3] = *(const bf16x8*)(pl + 3072);                               \
  } while (0)

  char* bufR = smem;
  char* bufM = smem + ABY;
  char* bufS = smem + 2 * ABY;

  SB;
  STAGE_A(bufR);                      // A(0)
  SB;
  LOAD_B(bh0, bl0, 0);                // B(0)
  SB;
  aoff = ASTEP;
  STAGE_A(bufM);                      // A(1)
  SB;
  LOAD_B(bh1, bl1, 4096);             // B(1)
  SB;
  aoff = (2 * ASTEP < amax) ? 2 * ASTEP : amax;
  boff = (2 * 4096 < bmax) ? 2 * 4096 : bmax;
  asm volatile("s_waitcnt vmcnt(%0)" ::"i"(W2N) : "memory");  // A(0) landed
  __builtin_amdgcn_s_barrier();
  SB;

#define KSTEP(BH, BL)                                                        \
  do {                                                                       \
    STAGE_A(bufS); /* A(kb+2) */                                             \
    aoff = (aoff < amax) ? aoff + ASTEP : aoff;                              \
    SB;                                                                      \
    bf16x8 af[FM];                                                           \
    _Pragma("unroll") for (int m = 0; m < FM; ++m) {                         \
      const int fr = wm * FM + m;                                            \
      af[m] = *(const bf16x8*)(bufR + (fr * 64 + lane) * 16);                \
    }                                                                        \
    SB;                                                                      \
    _Pragma("unroll") for (int m = 0; m < FM; ++m) {                         \
      _Pragma("unroll") for (int n = 0; n < 4; ++n) {                        \
        acc[m][n] = __builtin_amdgcn_mfma_f32_16x16x32_bf16(af[m], BH[n],    \
                                                            acc[m][n], 0, 0, 0); \
        acc[m][n] = __builtin_amdgcn_mfma_f32_16x16x32_bf16(af[m], BL[n],    \
                                                            acc[m][n], 0, 0, 0); \
      }                                                                      \
      if constexpr (LNFOLD)                                                  \
        acc1[m] = __builtin_amdgcn_mfma_f32_16x16x32_bf16(af[m], ONES,       \
                                                          acc1[m], 0, 0, 0); \
    }                                                                        \
    SB;                                                                      \
    LOAD_B(BH, BL, boff); /* B(kb+2) */                                      \
    boff = (boff < bmax) ? boff + 4096 : boff;                               \
    SB;                                                                      \
    asm volatile("s_waitcnt vmcnt(%0)" ::"i"(W2N) : "memory");               \
    __builtin_amdgcn_s_barrier();                                            \
    SB;                                                                      \
    { char* t = bufR; bufR = bufM; bufM = bufS; bufS = t; }                  \
  } while (0)

  const int ITER = KB / 2;
  for (int it = 0; it < ITER; ++it) {
    KSTEP(bh0, bl0);
    KSTEP(bh1, bl1);
  }
  asm volatile("s_waitcnt vmcnt(0) lgkmcnt(0)" ::: "memory");

#undef KSTEP
#undef LOAD_B
#undef STAGE_A

  const int row0w = row0 + wm * TM;
  const int col0w = col0 + wc * 64;
#pragma unroll
  for (int m = 0; m < FM; ++m) {
    const int rbase = row0w + m * 16 + l4 * 4;
    float iv[4], mv[4];
    if constexpr (LNFOLD) {
#pragma unroll
      for (int r = 0; r < 4; ++r) {
        const float mean = acc1[m][r] / (float)K;
        const float inv = 1.0f / sqrtf(mean * (1.f - mean) + 1e-6f);
        iv[r] = inv;
        mv[r] = mean * inv;
      }
    }
#pragma unroll
    for (int n = 0; n < 4; ++n) {
      const int c = col0w + n * 16 + l15;
      const float cc = cvec[c];
      float uu = 0.f;
      if constexpr (LNFOLD) uu = uvec[c];
#pragma unroll
      for (int r = 0; r < 4; ++r) {
        float v;
        if constexpr (LNFOLD) v = iv[r] * acc[m][n][r] - mv[r] * uu + cc;
        else v = acc[m][n][r] + cc;
        C[(size_t)(rbase + r) * N + c] = v;
      }
    }
  }
}

// ---------------------------------------------------------------------------
// Prep: W[K,N] f32 (optionally scaled by s[k]) -> split hi/lo bf16 in the
// fragment-linear (64-col-block) global layout consumed by the GEMMs.
// ---------------------------------------------------------------------------
__global__ void prep_split(const float* __restrict__ W, const float* __restrict__ s,
                           char* __restrict__ hi, char* __restrict__ lo,
                           int K, int N) {
  const int g = blockIdx.x * 256 + threadIdx.x;
  const int total = (K * N) / 8;
  if (g >= total) return;
  constexpr int UB = 256;
  const int KB = K / 32;
  const int unit = g % UB;
  const int kb = (g / UB) % KB;
  const int cb = g / (UB * KB);
  const int n = cb * 64 + ((unit >> 6) << 4) + (unit & 15);
  const int kbase = kb * 32 + ((unit >> 4) & 3) * 8;
  short h8[8], l8[8];
#pragma unroll
  for (int jj = 0; jj < 8; ++jj) {
    const int k = kbase + jj;
    float w = W[(size_t)k * N + n];
    if (s) w *= s[k];
    const unsigned short hb = f2bf_rne(w);
    const unsigned short lb = f2bf_rne(w - bf2f(hb));
    h8[jj] = (short)hb;
    l8[jj] = (short)lb;
  }
  *(bf16x8*)(hi + (size_t)g * 16) = *(const bf16x8*)h8;
  *(bf16x8*)(lo + (size_t)g * 16) = *(const bf16x8*)l8;
}

// u[n] = sum_k s[k]*W[k,n];  c[n] = sum_k b[k]*W[k,n] + bias2[n]. Block per n.
__global__ __launch_bounds__(256) void prep_consts(
    const float* __restrict__ W, const float* __restrict__ s,
    const float* __restrict__ b, const float* __restrict__ bias2,
    float* __restrict__ u, float* __restrict__ c, int K, int N) {
  const int n = blockIdx.x;
  const int t = threadIdx.x;
  float us = 0.f, cs = 0.f;
  for (int k = t; k < K; k += 256) {
    const float w = W[(size_t)k * N + n];
    us += s[k] * w;
    cs += b[k] * w;
  }
  __shared__ float su[256], sc[256];
  su[t] = us;
  sc[t] = cs;
  __syncthreads();
  for (int o = 128; o > 0; o >>= 1) {
    if (t < o) { su[t] += su[t + o]; sc[t] += sc[t + o]; }
    __syncthreads();
  }
  if (t == 0) { u[n] = su[0]; c[n] = sc[0] + bias2[n]; }
}

// ---------------------------------------------------------------------------
// LIF scan over T, one thread per (b,h); reads fp32 currents, writes bf16
// spikes (exact) and/or per-(b,h) spike counts. 32x unrolled loads.
// ---------------------------------------------------------------------------
template <int H, bool SPIKE_OUT, bool ACCUM>
__global__ void lif_scan(const float* __restrict__ xt,
                         unsigned short* __restrict__ sp,
                         float* __restrict__ tsum) {
  const int n = blockIdx.x * 64 + threadIdx.x;
  const int b = n / H, h = n % H;
  const float* p = xt + (size_t)b * T_STEPS * H + h;
  unsigned short* q = nullptr;
  if constexpr (SPIKE_OUT) q = sp + (size_t)b * T_STEPS * H + h;

  float v = 0.f, cur = 0.f, ts = 0.f;
  for (int t = 0; t < T_STEPS; t += 32) {
    float x[32];
#pragma unroll
    for (int u = 0; u < 32; ++u) x[u] = p[(size_t)u * H];
#pragma unroll
    for (int u = 0; u < 32; ++u) {
      cur = BETA_ * cur + x[u];
      v = ALPHA_ * v + cur;
      const bool sb = (v >= 1.f);
      if constexpr (SPIKE_OUT) q[(size_t)u * H] = sb ? 0x3F80 : 0;
      if constexpr (ACCUM) ts += sb ? 1.f : 0.f;
      v = sb ? 0.f : v;
    }
    p += (size_t)32 * H;
    if constexpr (SPIKE_OUT) q += (size_t)32 * H;
  }
  if constexpr (ACCUM) tsum[n] = ts;
}

__global__ void finalize(const float* __restrict__ tsum,
                         const float* __restrict__ Wc,
                         const float* __restrict__ bc,
                         float* __restrict__ out) {
  const int b = threadIdx.x;  // 64 threads, one wave
  float s = 0.f;
#pragma unroll 8
  for (int h = 0; h < 64; ++h) s += tsum[b * 64 + h];
  const float pooled = s * (1.0f / (512.f * 64.f));
  out[2 + b] = pooled;

  float tot = pooled;
  float l0 = pooled * Wc[b * 2 + 0];
  float l1 = pooled * Wc[b * 2 + 1];
#pragma unroll
  for (int off = 32; off > 0; off >>= 1) {
    tot += __shfl_xor(tot, off);
    l0 += __shfl_xor(l0, off);
    l1 += __shfl_xor(l1, off);
  }
  if (b == 0) {
    out[0] = l0 + bc[0];
    out[1] = l1 + bc[1];
    out[66] = tot * (1.0f / 64.f);
  }
}

extern "C" void kernel_launch(void* const* d_in, const int* in_sizes, int n_in,
                              void* d_out, int out_size, void* d_ws, size_t ws_size,
                              hipStream_t stream) {
  const float* X    = (const float*)d_in[0];   // [64,512,64,16] -> [32768,1024]
  const float* W0   = (const float*)d_in[1];   // [1024,256]
  const float* b0   = (const float*)d_in[2];
  const float* W1   = (const float*)d_in[3];   // [256,128]
  const float* b1   = (const float*)d_in[4];
  const float* W2   = (const float*)d_in[5];   // [128,64]
  const float* b2   = (const float*)d_in[6];
  const float* ln1s = (const float*)d_in[7];
  const float* ln1b = (const float*)d_in[8];
  const float* ln2s = (const float*)d_in[9];
  const float* ln2b = (const float*)d_in[10];
  const float* Wc   = (const float*)d_in[11];  // [64,2]
  const float* bc   = (const float*)d_in[12];
  float* out = (float*)d_out;

  char* w = (char*)d_ws;
  float* buf0 = (float*)w;                       // [32768,256] f32 = 33554432 B
  float* buf1 = (float*)w;                       // alias: buf0 dead after scan0
  float* buf2 = (float*)(w + 16777216);          // [32768,64] f32, after buf1
  size_t off = 33554432;
  unsigned short* sp0 = (unsigned short*)(w + off); off += 16777216;  // [32768,256] bf16
  unsigned short* sp1 = (unsigned short*)(w + off); off += 8388608;   // [32768,128] bf16
  char* hi0 = w + off; off += 524288;
  char* lo0 = w + off; off += 524288;
  char* hi1 = w + off; off += 65536;
  char* lo1 = w + off; off += 65536;
  char* hi2 = w + off; off += 16384;
  char* lo2 = w + off; off += 16384;
  float* u1 = (float*)(w + off); off += 512;
  float* c1 = (float*)(w + off); off += 512;
  float* u2 = (float*)(w + off); off += 256;
  float* c2 = (float*)(w + off); off += 256;
  float* tsum = (float*)(w + off); off += 16384;

  const int M = 32768;

  // --- weight prep (frag-linear 64-col-block split hi/lo + LN-fold consts) ---
  prep_split<<<128, 256, 0, stream>>>(W0, nullptr, hi0, lo0, 1024, 256);
  prep_split<<<16, 256, 0, stream>>>(W1, ln1s, hi1, lo1, 256, 128);
  prep_split<<<4, 256, 0, stream>>>(W2, ln2s, hi2, lo2, 128, 64);
  prep_consts<<<128, 256, 0, stream>>>(W1, ln1s, ln1b, b1, u1, c1, 256, 128);
  prep_consts<<<64, 256, 0, stream>>>(W2, ln2s, ln2b, b2, u2, c2, 128, 64);

  // --- layer 0: BK=64 step-count experiment. BM=64, BN=128, grid (2,512),
  //     16 K-steps of 32 MFMA/wave; COAL A staging; counted vmcnt(36). ---
  gemm_bk64<<<dim3(2, M / 64), 256, 0, stream>>>(
      X, hi0, lo0, b0, buf0, 256, 1024);
  lif_scan<256, true, false><<<(BATCH * 256) / 64, 64, 0, stream>>>(buf0, sp0, nullptr);

  // --- layer 1: LN folded (rowsum via ones-MFMA). R15 config. ---
  gemm_deep2<2, 2, 32, true><<<dim3(1, M / 64), 256, 0, stream>>>(
      sp0, hi1, lo1, u1, c1, buf1, 128, 256);
  lif_scan<128, true, false><<<(BATCH * 128) / 64, 64, 0, stream>>>(buf1, sp1, nullptr);

  // --- layer 2: R15 config (BM=128). ---
  gemm_deep2<4, 1, 32, true><<<dim3(1, M / 128), 256, 0, stream>>>(
      sp1, hi2, lo2, u2, c2, buf2, 64, 128);
  lif_scan<64, false, true><<<(BATCH * 64) / 64, 64, 0, stream>>>(buf2, nullptr, tsum);

  finalize<<<1, 64, 0, stream>>>(tsum, Wc, bc, out);
}

// Round 18
// 147.410 us; speedup vs baseline: 1.0665x; 1.0665x over previous
//
#include <hip/hip_runtime.h>

#define T_STEPS 512
#define BATCH 64

// fp32 casts of np.exp(-1/20), np.exp(-1/5)
__device__ constexpr float ALPHA_ = 0.95122942450071400910f;
__device__ constexpr float BETA_  = 0.81873075307798185867f;

typedef __attribute__((ext_vector_type(4))) int   i32x4;
typedef __attribute__((ext_vector_type(4))) float f32x4;

__device__ inline void gload16(const void* g, void* l) {
  __builtin_amdgcn_global_load_lds(
      (const __attribute__((address_space(1))) unsigned int*)g,
      (__attribute__((address_space(3))) unsigned int*)l, 16, 0, 0);
}

// 4 spike floats (0.0/1.0) -> 4 packed i8 (exact: bit29 of 1.0f is 1)
__device__ inline int pack4(f32x4 v) {
  return (int)(((__float_as_uint(v.x) >> 29) & 1u) |
               (((__float_as_uint(v.y) >> 29) & 1u) << 8) |
               (((__float_as_uint(v.z) >> 29) & 1u) << 16) |
               (((__float_as_uint(v.w) >> 29) & 1u) << 24));
}

// ---------------------------------------------------------------------------
// scale slots via deterministic atomicMax
// ---------------------------------------------------------------------------
__global__ void zero_slots(unsigned int* __restrict__ slots) {
  if (threadIdx.x < 3) slots[threadIdx.x] = 0u;
}

__global__ void prep_maxabs(const float* __restrict__ W, const float* __restrict__ s,
                            unsigned int* __restrict__ slot, int K, int N) {
  const int stride = gridDim.x * 256;
  float m = 0.f;
  for (int i = blockIdx.x * 256 + threadIdx.x; i < K * N; i += stride) {
    float w = W[i];
    if (s) w *= s[i / N];
    m = fmaxf(m, fabsf(w));
  }
#pragma unroll
  for (int o = 32; o > 0; o >>= 1) m = fmaxf(m, __shfl_xor(m, o));
  if ((threadIdx.x & 63) == 0) atomicMax(slot, __float_as_uint(m));
}

// ---------------------------------------------------------------------------
// Two-level i8 quantization of W (opt. LN-scale s[k] folded), frag-linear:
// unit g: lane=g&63; per16=g>>6; nf=per16%NF; lv=(per16/NF)&1; kb=per16/(2NF).
// n = nf*16+(lane&15); k = kb*64+((lane>>4)<<4)+jj.
// w ~= s1*q1 + s2*q2, s1=max/127, s2=s1/254 -> |err| <= s1/508.
// ---------------------------------------------------------------------------
__global__ void prep_quant(const float* __restrict__ W, const float* __restrict__ s,
                           const unsigned int* __restrict__ slot,
                           char* __restrict__ Bq, int K, int N) {
  const int NF = N / 16;
  const int g = blockIdx.x * 256 + threadIdx.x;
  const int total = (K / 64) * 2 * NF * 64;
  if (g >= total) return;
  const float maxv = fmaxf(__uint_as_float(*slot), 1e-30f);
  const float s1 = maxv * (1.0f / 127.0f);
  const float s2 = s1 * (1.0f / 254.0f);
  const float inv1 = 1.0f / s1, inv2 = 1.0f / s2;
  const int lane = g & 63;
  const int per16 = g >> 6;
  const int nf = per16 % NF;
  const int lv = (per16 / NF) & 1;
  const int kb = per16 / (2 * NF);
  const int n = nf * 16 + (lane & 15);
  const int kbase = kb * 64 + ((lane >> 4) << 4);
  unsigned int wq[4] = {0, 0, 0, 0};
#pragma unroll
  for (int jj = 0; jj < 16; ++jj) {
    const int k = kbase + jj;
    float w = W[(size_t)k * N + n];
    if (s) w *= s[k];
    const int q1 = (int)rintf(w * inv1);
    int q;
    if (lv == 0) {
      q = q1;
    } else {
      const float r = w - (float)q1 * s1;
      q = (int)rintf(r * inv2);
    }
    wq[jj >> 2] |= ((unsigned int)(q & 0xFF)) << ((jj & 3) * 8);
  }
  i32x4 v;
#pragma unroll
  for (int q = 0; q < 4; ++q) v[q] = (int)wq[q];
  *(i32x4*)(Bq + (size_t)g * 16) = v;
}

// ---------------------------------------------------------------------------
// MINIMUM-TRAFFIC i8 GEMM (the R17 cross-round law: duration = VMEM bytes /
// ~10 TB/s cap -> minimize bytes). BM=128, BN=N (full width), BK=64,
// 512 threads (8 waves, WM=2 x WC=4), grid = M/128 = 256 (1 block/CU).
//   B: two-level i8, staged ONCE per block-step into LDS via linear
//      gload_lds (frag-linear global) — read-once-per-block traffic.
//   A_F32: fp32 spikes reg-loaded COALESCED (4 rows x 256 B per instr),
//      packed to i8 in-register (exact), ONE ds_write_b128/thread into a
//      frag-linear i8 LDS tile (4x smaller frag reads than fp32 tile).
//   A_F32=false: A already i8 in global; gload_lds direct (16B/lane frags).
//   Double-buffered, prefetch issued at step top, one __syncthreads()/step
//   (R3/R5/R8 proved sync structure is not the lever; traffic is).
//   i32 accumulation is EXACT -> result independent of K order; epilogue
//   dot = s1*acc1 + s2*acc2 (identical math to R12, absmax 0.001953125).
// LNFOLD: rowsum via ones-i8 MFMA (exact ints); inv*dot - mi*u + c.
// ---------------------------------------------------------------------------
template <int BN, bool A_F32, bool LNFOLD>
__global__ __launch_bounds__(512) void gemm_i8w(
    const void* __restrict__ Av, const char* __restrict__ Bq,
    const unsigned int* __restrict__ slot, const float* __restrict__ uvec,
    const float* __restrict__ cvec, float* __restrict__ C, int N, int K) {
  constexpr int NF = BN / 16;        // 16-col fragments per step
  constexpr int NFPW = BN / 64;      // n-frags per wave (WC=4)
  constexpr int BSTEP = NF * 2048;   // B bytes per step (2 levels)
  constexpr int BGPT = (BSTEP / 16) / 512;  // B gloads per thread
  __shared__ char Abuf[2][8192];     // 128 rows x 64 k i8, frag-linear
  __shared__ char Bbuf[2][BSTEP];    // [lv][nf][lane][16]

  const int tid = threadIdx.x;
  const int lane = tid & 63;
  const int wave = tid >> 6;
  const int wm = wave >> 2, wc = wave & 3;
  const int l15 = lane & 15, l4 = lane >> 4;
  const int row0 = blockIdx.x * 128;
  const int KB = K / 64;

  const char* Ab = (const char*)Av;

  // A source/dest (per thread)
  const char* a_src;
  int a_dst;
  if constexpr (A_F32) {
    // thread t: row = t>>2, 16 floats starting at (t&3)*16 within step slice
    a_src = Ab + ((size_t)(row0 + (tid >> 2)) * K + (tid & 3) * 16) * 4;
    const int lp = (tid & 3) * 16 + ((tid >> 2) & 15);
    a_dst = (tid >> 6) * 1024 + lp * 16;
  } else {
    // i8 global row-major: per-lane 16B frag gather
    a_src = Ab + (size_t)(row0 + (tid >> 6) * 16 + l15) * K + (l4 << 4);
    a_dst = tid * 16;
  }
  const char* b_src = Bq + (size_t)tid * 16;  // + kb*BSTEP + i*512*16

  i32x4 acc1[4][NFPW] = {};
  i32x4 acc2[4][NFPW] = {};
  i32x4 accR[4] = {};
  const i32x4 ONESB = {0x01010101, 0x01010101, 0x01010101, 0x01010101};

  f32x4 ar0, ar1, ar2, ar3;  // A_F32 staging regs (named, static)

  // ---- prologue: stage kb=0 ----
  if constexpr (A_F32) {
    const float* p = (const float*)a_src;
    ar0 = *(const f32x4*)(p + 0);
    ar1 = *(const f32x4*)(p + 4);
    ar2 = *(const f32x4*)(p + 8);
    ar3 = *(const f32x4*)(p + 12);
  } else {
    gload16(a_src, Abuf[0] + a_dst);
  }
#pragma unroll
  for (int i = 0; i < BGPT; ++i)
    gload16(b_src + i * 8192, Bbuf[0] + (i * 512 + tid) * 16);
  if constexpr (A_F32) {
    i32x4 pk = {pack4(ar0), pack4(ar1), pack4(ar2), pack4(ar3)};
    *(i32x4*)(Abuf[0] + a_dst) = pk;
  }
  __syncthreads();

  for (int kb = 0; kb < KB; ++kb) {
    const int cur = kb & 1, nxt = cur ^ 1;
    const bool pf = (kb + 1 < KB);

    // --- issue next-step loads at the top ---
    if (pf) {
      if constexpr (A_F32) {
        const float* p = (const float*)(a_src + (size_t)(kb + 1) * 256);
        ar0 = *(const f32x4*)(p + 0);
        ar1 = *(const f32x4*)(p + 4);
        ar2 = *(const f32x4*)(p + 8);
        ar3 = *(const f32x4*)(p + 12);
      } else {
        gload16(a_src + (size_t)(kb + 1) * 64, Abuf[nxt] + a_dst);
      }
      const char* bs = b_src + (size_t)(kb + 1) * BSTEP;
#pragma unroll
      for (int i = 0; i < BGPT; ++i)
        gload16(bs + i * 8192, Bbuf[nxt] + (i * 512 + tid) * 16);
    }

    // --- compute current step ---
    i32x4 af[4];
#pragma unroll
    for (int m = 0; m < 4; ++m)
      af[m] = *(const i32x4*)(Abuf[cur] + ((wm * 4 + m) * 64 + lane) * 16);
    i32x4 b1[NFPW], b2[NFPW];
#pragma unroll
    for (int n = 0; n < NFPW; ++n) {
      b1[n] = *(const i32x4*)(Bbuf[cur] + ((wc * NFPW + n) * 64 + lane) * 16);
      b2[n] = *(const i32x4*)(Bbuf[cur] + ((NF + wc * NFPW + n) * 64 + lane) * 16);
    }
#pragma unroll
    for (int m = 0; m < 4; ++m) {
#pragma unroll
      for (int n = 0; n < NFPW; ++n) {
        acc1[m][n] = __builtin_amdgcn_mfma_i32_16x16x64_i8(af[m], b1[n], acc1[m][n], 0, 0, 0);
        acc2[m][n] = __builtin_amdgcn_mfma_i32_16x16x64_i8(af[m], b2[n], acc2[m][n], 0, 0, 0);
      }
      if constexpr (LNFOLD)
        accR[m] = __builtin_amdgcn_mfma_i32_16x16x64_i8(af[m], ONESB, accR[m], 0, 0, 0);
    }

    // --- pack+write A(kb+1) (regs arrived during compute) ---
    if (pf && A_F32) {
      i32x4 pk = {pack4(ar0), pack4(ar1), pack4(ar2), pack4(ar3)};
      *(i32x4*)(Abuf[nxt] + a_dst) = pk;
    }
    __syncthreads();  // drains gload_lds + ds ops; next buffers ready
  }

  // ---- epilogue ----
  const float maxv = fmaxf(__uint_as_float(*slot), 1e-30f);
  const float s1 = maxv * (1.0f / 127.0f);
  const float s2 = s1 * (1.0f / 254.0f);
#pragma unroll
  for (int m = 0; m < 4; ++m) {
    const int rbase = row0 + wm * 64 + m * 16 + l4 * 4;
    float iv[4], mv[4];
    if constexpr (LNFOLD) {
#pragma unroll
      for (int r = 0; r < 4; ++r) {
        const float mean = (float)accR[m][r] / (float)K;
        const float inv = 1.0f / sqrtf(mean * (1.f - mean) + 1e-6f);
        iv[r] = inv;
        mv[r] = mean * inv;
      }
    }
#pragma unroll
    for (int n = 0; n < NFPW; ++n) {
      const int c = (wc * NFPW + n) * 16 + l15;
      const float cc = cvec[c];
      float uu = 0.f;
      if constexpr (LNFOLD) uu = uvec[c];
#pragma unroll
      for (int r = 0; r < 4; ++r) {
        const float dot = s1 * (float)acc1[m][n][r] + s2 * (float)acc2[m][n][r];
        float v;
        if constexpr (LNFOLD) v = iv[r] * dot - mv[r] * uu + cc;
        else v = dot + cc;
        C[(size_t)(rbase + r) * N + c] = v;
      }
    }
  }
}

// u[n] = sum_k s[k]*W[k,n];  c[n] = sum_k b[k]*W[k,n] + bias2[n]. Block per n.
__global__ __launch_bounds__(256) void prep_consts(
    const float* __restrict__ W, const float* __restrict__ s,
    const float* __restrict__ b, const float* __restrict__ bias2,
    float* __restrict__ u, float* __restrict__ c, int K, int N) {
  const int n = blockIdx.x;
  const int t = threadIdx.x;
  float us = 0.f, cs = 0.f;
  for (int k = t; k < K; k += 256) {
    const float w = W[(size_t)k * N + n];
    us += s[k] * w;
    cs += b[k] * w;
  }
  __shared__ float su[256], sc[256];
  su[t] = us;
  sc[t] = cs;
  __syncthreads();
  for (int o = 128; o > 0; o >>= 1) {
    if (t < o) { su[t] += su[t + o]; sc[t] += sc[t + o]; }
    __syncthreads();
  }
  if (t == 0) { u[n] = su[0]; c[n] = sc[0] + bias2[n]; }
}

// ---------------------------------------------------------------------------
// LIF scan over T, one thread per (b,h); reads fp32 currents, writes i8
// spikes (1/0) and/or per-(b,h) spike counts. 32x unrolled loads.
// ---------------------------------------------------------------------------
template <int H, bool SPIKE_OUT, bool ACCUM>
__global__ void lif_scan(const float* __restrict__ xt,
                         char* __restrict__ sp,
                         float* __restrict__ tsum) {
  const int n = blockIdx.x * 64 + threadIdx.x;
  const int b = n / H, h = n % H;
  const float* p = xt + (size_t)b * T_STEPS * H + h;
  char* q = nullptr;
  if constexpr (SPIKE_OUT) q = sp + (size_t)b * T_STEPS * H + h;

  float v = 0.f, cur = 0.f, ts = 0.f;
  for (int t = 0; t < T_STEPS; t += 32) {
    float x[32];
#pragma unroll
    for (int u = 0; u < 32; ++u) x[u] = p[(size_t)u * H];
#pragma unroll
    for (int u = 0; u < 32; ++u) {
      cur = BETA_ * cur + x[u];
      v = ALPHA_ * v + cur;
      const bool sb = (v >= 1.f);
      if constexpr (SPIKE_OUT) q[(size_t)u * H] = sb ? (char)1 : (char)0;
      if constexpr (ACCUM) ts += sb ? 1.f : 0.f;
      v = sb ? 0.f : v;
    }
    p += (size_t)32 * H;
    if constexpr (SPIKE_OUT) q += (size_t)32 * H;
  }
  if constexpr (ACCUM) tsum[n] = ts;
}

__global__ void finalize(const float* __restrict__ tsum,
                         const float* __restrict__ Wc,
                         const float* __restrict__ bc,
                         float* __restrict__ out) {
  const int b = threadIdx.x;  // 64 threads, one wave
  float s = 0.f;
#pragma unroll 8
  for (int h = 0; h < 64; ++h) s += tsum[b * 64 + h];
  const float pooled = s * (1.0f / (512.f * 64.f));
  out[2 + b] = pooled;

  float tot = pooled;
  float l0 = pooled * Wc[b * 2 + 0];
  float l1 = pooled * Wc[b * 2 + 1];
#pragma unroll
  for (int off = 32; off > 0; off >>= 1) {
    tot += __shfl_xor(tot, off);
    l0 += __shfl_xor(l0, off);
    l1 += __shfl_xor(l1, off);
  }
  if (b == 0) {
    out[0] = l0 + bc[0];
    out[1] = l1 + bc[1];
    out[66] = tot * (1.0f / 64.f);
  }
}

extern "C" void kernel_launch(void* const* d_in, const int* in_sizes, int n_in,
                              void* d_out, int out_size, void* d_ws, size_t ws_size,
                              hipStream_t stream) {
  const float* X    = (const float*)d_in[0];   // [64,512,64,16] -> [32768,1024]
  const float* W0   = (const float*)d_in[1];   // [1024,256]
  const float* b0   = (const float*)d_in[2];
  const float* W1   = (const float*)d_in[3];   // [256,128]
  const float* b1   = (const float*)d_in[4];
  const float* W2   = (const float*)d_in[5];   // [128,64]
  const float* b2   = (const float*)d_in[6];
  const float* ln1s = (const float*)d_in[7];
  const float* ln1b = (const float*)d_in[8];
  const float* ln2s = (const float*)d_in[9];
  const float* ln2b = (const float*)d_in[10];
  const float* Wc   = (const float*)d_in[11];  // [64,2]
  const float* bc   = (const float*)d_in[12];
  float* out = (float*)d_out;

  char* w = (char*)d_ws;
  float* buf0 = (float*)w;                   // [32768,256] f32 = 33554432 B
  float* buf1 = (float*)w;                   // alias: buf0 dead after scan0
  float* buf2 = (float*)(w + 16777216);      // [32768,64] f32
  size_t off = 33554432;
  char* sp0 = w + off; off += 8388608;       // [32768,256] i8
  char* sp1 = w + off; off += 4194304;       // [32768,128] i8
  char* bq0 = w + off; off += 524288;        // W0 two-level i8 frag-linear
  char* bq1 = w + off; off += 65536;
  char* bq2 = w + off; off += 16384;
  float* u1 = (float*)(w + off); off += 512;
  float* c1 = (float*)(w + off); off += 512;
  float* u2 = (float*)(w + off); off += 256;
  float* c2 = (float*)(w + off); off += 256;
  unsigned int* slots = (unsigned int*)(w + off); off += 256;
  float* tsum = (float*)(w + off); off += 16384;

  const int M = 32768;

  // --- scales + two-level i8 weight prep + LN-fold constants ---
  zero_slots<<<1, 64, 0, stream>>>(slots);
  prep_maxabs<<<64, 256, 0, stream>>>(W0, nullptr, slots + 0, 1024, 256);
  prep_maxabs<<<16, 256, 0, stream>>>(W1, ln1s, slots + 1, 256, 128);
  prep_maxabs<<<8, 256, 0, stream>>>(W2, ln2s, slots + 2, 128, 64);
  prep_quant<<<128, 256, 0, stream>>>(W0, nullptr, slots + 0, bq0, 1024, 256);
  prep_quant<<<16, 256, 0, stream>>>(W1, ln1s, slots + 1, bq1, 256, 128);
  prep_quant<<<4, 256, 0, stream>>>(W2, ln2s, slots + 2, bq2, 128, 64);
  prep_consts<<<128, 256, 0, stream>>>(W1, ln1s, ln1b, b1, u1, c1, 256, 128);
  prep_consts<<<64, 256, 0, stream>>>(W2, ln2s, ln2b, b2, u2, c2, 128, 64);

  // --- layer 0: xt = X @ W0 + b0. Min-traffic i8 GEMM: BM=128, BN=256,
  //     grid 256 (1 block/CU), B staged once/block, A fp32 read once. ---
  gemm_i8w<256, true, false><<<M / 128, 512, 0, stream>>>(
      X, bq0, slots + 0, nullptr, b0, buf0, 256, 1024);
  lif_scan<256, true, false><<<(BATCH * 256) / 64, 64, 0, stream>>>(buf0, sp0, nullptr);

  // --- layer 1: LN folded (rowsum via ones-MFMA). BN=128. ---
  gemm_i8w<128, false, true><<<M / 128, 512, 0, stream>>>(
      sp0, bq1, slots + 1, u1, c1, buf1, 128, 256);
  lif_scan<128, true, false><<<(BATCH * 128) / 64, 64, 0, stream>>>(buf1, sp1, nullptr);

  // --- layer 2: BN=64. ---
  gemm_i8w<64, false, true><<<M / 128, 512, 0, stream>>>(
      sp1, bq2, slots + 2, u2, c2, buf2, 64, 128);
  lif_scan<64, false, true><<<(BATCH * 64) / 64, 64, 0, stream>>>(buf2, nullptr, tsum);

  finalize<<<1, 64, 0, stream>>>(tsum, Wc, bc, out);
}

// Round 19
// 135.595 us; speedup vs baseline: 1.1594x; 1.0871x over previous
//
#include <hip/hip_runtime.h>

#define T_STEPS 512
#define BATCH 64

// fp32 casts of np.exp(-1/20), np.exp(-1/5)
__device__ constexpr float ALPHA_ = 0.95122942450071400910f;
__device__ constexpr float BETA_  = 0.81873075307798185867f;

typedef __attribute__((ext_vector_type(8))) short bf16x8;
typedef __attribute__((ext_vector_type(4))) int   i32x4;
typedef __attribute__((ext_vector_type(4))) float f32x4;

__device__ inline unsigned short f2bf_rne(float f) {
  union { float f; unsigned int u; } v{f};
  const unsigned int u = v.u;
  return (unsigned short)((u + 0x7FFFu + ((u >> 16) & 1u)) >> 16);
}
__device__ inline float bf2f(unsigned short h) {
  union { unsigned int u; float f; } v{(unsigned int)h << 16};
  return v.f;
}

__device__ inline void gload16(const void* g, void* l) {
  __builtin_amdgcn_global_load_lds(
      (const __attribute__((address_space(1))) unsigned int*)g,
      (__attribute__((address_space(3))) unsigned int*)l, 16, 0, 0);
}

// 4 spike floats (0.0/1.0) -> 4 packed i8 (exact: bit29 of 1.0f is 1)
__device__ inline int pack4(f32x4 v) {
  return (int)(((__float_as_uint(v.x) >> 29) & 1u) |
               (((__float_as_uint(v.y) >> 29) & 1u) << 8) |
               (((__float_as_uint(v.z) >> 29) & 1u) << 16) |
               (((__float_as_uint(v.w) >> 29) & 1u) << 24));
}

#define SB __builtin_amdgcn_sched_barrier(0)

// ===========================================================================
//  L0 PATH: minimum-traffic two-level-i8 GEMM (R18, proven < 74.4 us)
// ===========================================================================
__global__ void zero_slots(unsigned int* __restrict__ slots) {
  if (threadIdx.x < 1) slots[threadIdx.x] = 0u;
}

__global__ void prep_maxabs(const float* __restrict__ W,
                            unsigned int* __restrict__ slot, int KN) {
  const int stride = gridDim.x * 256;
  float m = 0.f;
  for (int i = blockIdx.x * 256 + threadIdx.x; i < KN; i += stride)
    m = fmaxf(m, fabsf(W[i]));
#pragma unroll
  for (int o = 32; o > 0; o >>= 1) m = fmaxf(m, __shfl_xor(m, o));
  if ((threadIdx.x & 63) == 0) atomicMax(slot, __float_as_uint(m));
}

// Two-level i8 quant of W0 [K,N] -> frag-linear (see gemm_i8w layout).
__global__ void prep_quant(const float* __restrict__ W,
                           const unsigned int* __restrict__ slot,
                           char* __restrict__ Bq, int K, int N) {
  const int NF = N / 16;
  const int g = blockIdx.x * 256 + threadIdx.x;
  const int total = (K / 64) * 2 * NF * 64;
  if (g >= total) return;
  const float maxv = fmaxf(__uint_as_float(*slot), 1e-30f);
  const float s1 = maxv * (1.0f / 127.0f);
  const float s2 = s1 * (1.0f / 254.0f);
  const float inv1 = 1.0f / s1, inv2 = 1.0f / s2;
  const int lane = g & 63;
  const int per16 = g >> 6;
  const int nf = per16 % NF;
  const int lv = (per16 / NF) & 1;
  const int kb = per16 / (2 * NF);
  const int n = nf * 16 + (lane & 15);
  const int kbase = kb * 64 + ((lane >> 4) << 4);
  unsigned int wq[4] = {0, 0, 0, 0};
#pragma unroll
  for (int jj = 0; jj < 16; ++jj) {
    const int k = kbase + jj;
    const float w = W[(size_t)k * N + n];
    const int q1 = (int)rintf(w * inv1);
    int q;
    if (lv == 0) {
      q = q1;
    } else {
      const float r = w - (float)q1 * s1;
      q = (int)rintf(r * inv2);
    }
    wq[jj >> 2] |= ((unsigned int)(q & 0xFF)) << ((jj & 3) * 8);
  }
  i32x4 v;
#pragma unroll
  for (int q = 0; q < 4; ++q) v[q] = (int)wq[q];
  *(i32x4*)(Bq + (size_t)g * 16) = v;
}

// Min-traffic i8 GEMM for L0: BM=128, BN=256 (full N), BK=64, 512 thr,
// grid = 256 (1 block/CU). B staged once/block/step via gload_lds; A fp32
// reg-loaded coalesced, packed to i8 in-register (exact), ds_write frag-
// linear; double-buffered, one __syncthreads/step. i32 accum = exact.
__global__ __launch_bounds__(512) void gemm_i8w(
    const float* __restrict__ A, const char* __restrict__ Bq,
    const unsigned int* __restrict__ slot, const float* __restrict__ cvec,
    float* __restrict__ C, int N, int K) {
  constexpr int NF = 16;             // 256/16
  constexpr int BSTEP = NF * 2048;   // 32 KB per step (2 levels)
  constexpr int BGPT = (BSTEP / 16) / 512;  // 4
  __shared__ char Abuf[2][8192];
  __shared__ char Bbuf[2][BSTEP];

  const int tid = threadIdx.x;
  const int lane = tid & 63;
  const int wave = tid >> 6;
  const int wm = wave >> 2, wc = wave & 3;
  const int l15 = lane & 15, l4 = lane >> 4;
  const int row0 = blockIdx.x * 128;
  const int KB = K / 64;

  const char* a_src = (const char*)A + ((size_t)(row0 + (tid >> 2)) * K + (tid & 3) * 16) * 4;
  const int lp = (tid & 3) * 16 + ((tid >> 2) & 15);
  const int a_dst = (tid >> 6) * 1024 + lp * 16;
  const char* b_src = Bq + (size_t)tid * 16;

  i32x4 acc1[4][4] = {};
  i32x4 acc2[4][4] = {};

  f32x4 ar0, ar1, ar2, ar3;

  // ---- prologue ----
  {
    const float* p = (const float*)a_src;
    ar0 = *(const f32x4*)(p + 0);
    ar1 = *(const f32x4*)(p + 4);
    ar2 = *(const f32x4*)(p + 8);
    ar3 = *(const f32x4*)(p + 12);
  }
#pragma unroll
  for (int i = 0; i < BGPT; ++i)
    gload16(b_src + i * 8192, Bbuf[0] + (i * 512 + tid) * 16);
  {
    i32x4 pk = {pack4(ar0), pack4(ar1), pack4(ar2), pack4(ar3)};
    *(i32x4*)(Abuf[0] + a_dst) = pk;
  }
  __syncthreads();

  for (int kb = 0; kb < KB; ++kb) {
    const int cur = kb & 1, nxt = cur ^ 1;
    const bool pf = (kb + 1 < KB);

    if (pf) {
      const float* p = (const float*)(a_src + (size_t)(kb + 1) * 256);
      ar0 = *(const f32x4*)(p + 0);
      ar1 = *(const f32x4*)(p + 4);
      ar2 = *(const f32x4*)(p + 8);
      ar3 = *(const f32x4*)(p + 12);
      const char* bs = b_src + (size_t)(kb + 1) * BSTEP;
#pragma unroll
      for (int i = 0; i < BGPT; ++i)
        gload16(bs + i * 8192, Bbuf[nxt] + (i * 512 + tid) * 16);
    }

    i32x4 af[4];
#pragma unroll
    for (int m = 0; m < 4; ++m)
      af[m] = *(const i32x4*)(Abuf[cur] + ((wm * 4 + m) * 64 + lane) * 16);
    i32x4 b1[4], b2[4];
#pragma unroll
    for (int n = 0; n < 4; ++n) {
      b1[n] = *(const i32x4*)(Bbuf[cur] + ((wc * 4 + n) * 64 + lane) * 16);
      b2[n] = *(const i32x4*)(Bbuf[cur] + ((NF + wc * 4 + n) * 64 + lane) * 16);
    }
#pragma unroll
    for (int m = 0; m < 4; ++m)
#pragma unroll
      for (int n = 0; n < 4; ++n) {
        acc1[m][n] = __builtin_amdgcn_mfma_i32_16x16x64_i8(af[m], b1[n], acc1[m][n], 0, 0, 0);
        acc2[m][n] = __builtin_amdgcn_mfma_i32_16x16x64_i8(af[m], b2[n], acc2[m][n], 0, 0, 0);
      }

    if (pf) {
      i32x4 pk = {pack4(ar0), pack4(ar1), pack4(ar2), pack4(ar3)};
      *(i32x4*)(Abuf[nxt] + a_dst) = pk;
    }
    __syncthreads();
  }

  // ---- epilogue ----
  const float maxv = fmaxf(__uint_as_float(*slot), 1e-30f);
  const float s1 = maxv * (1.0f / 127.0f);
  const float s2 = s1 * (1.0f / 254.0f);
#pragma unroll
  for (int m = 0; m < 4; ++m) {
    const int rbase = row0 + wm * 64 + m * 16 + l4 * 4;
#pragma unroll
    for (int n = 0; n < 4; ++n) {
      const int c = (wc * 4 + n) * 16 + l15;
      const float cc = cvec[c];
#pragma unroll
      for (int r = 0; r < 4; ++r) {
        const float dot = s1 * (float)acc1[m][n][r] + s2 * (float)acc2[m][n][r];
        C[(size_t)(rbase + r) * N + c] = dot + cc;
      }
    }
  }
}

// ===========================================================================
//  L1/L2 PATH: R15 best — bf16 hi/lo deep-pipelined GEMM + bf16 spikes
// ===========================================================================
template <int WM, int WC, int TM, bool LNFOLD>
__global__ __launch_bounds__(256) void gemm_deep2(
    const void* __restrict__ Av, const char* __restrict__ Bhi,
    const char* __restrict__ Blo, const float* __restrict__ uvec,
    const float* __restrict__ cvec, float* __restrict__ C, int N, int K) {
  constexpr int BM = WM * TM;
  constexpr int FM = TM / 16;
  constexpr int ABY = BM * 64;
  constexpr int AIP = ABY / 4096;
  constexpr int ASTEP = 64;
  constexpr int W2N = AIP + 16;
  __shared__ char smem[3 * ABY];

  const int tid = threadIdx.x;
  const int lane = tid & 63;
  const int wave = tid >> 6;
  const int wm = wave / WC, wc = wave % WC;
  const int l15 = lane & 15, l4 = lane >> 4;
  const int row0 = blockIdx.y * BM;
  const int col0 = blockIdx.x * (WC * 64);
  const int KB = K / 32;

  const char* Ab = (const char*)Av;

  const char* a_src[AIP];
#pragma unroll
  for (int i = 0; i < AIP; ++i) {
    const int unit = i * 256 + tid;
    const int r = ((unit >> 6) << 4) | (unit & 15);
    const int j = (unit >> 4) & 3;
    a_src[i] = Ab + ((size_t)(row0 + r) * K + j * 8) * 2;
  }
  const char* bh_base = Bhi + (size_t)(blockIdx.x * WC + wc) * KB * 4096 + (size_t)lane * 16;
  const char* bl_base = Blo + (size_t)(blockIdx.x * WC + wc) * KB * 4096 + (size_t)lane * 16;

  int aoff = 0, boff = 0;
  const int amax = (KB - 1) * ASTEP;
  const int bmax = (KB - 1) * 4096;

  f32x4 acc[FM][4] = {};
  f32x4 acc1[FM] = {};
  const bf16x8 ONES = {0x3F80, 0x3F80, 0x3F80, 0x3F80,
                       0x3F80, 0x3F80, 0x3F80, 0x3F80};
  bf16x8 bh0[4], bl0[4], bh1[4], bl1[4];

#define STAGE_A(buf)                                                   \
  do {                                                                 \
    _Pragma("unroll") for (int i = 0; i < AIP; ++i)                    \
        gload16(a_src[i] + aoff, (buf) + (i * 256 + tid) * 16);        \
  } while (0)

#define LOAD_B(bh, bl, off_)                                           \
  do {                                                                 \
    const char* ph = bh_base + (off_);                                 \
    const char* pl = bl_base + (off_);                                 \
    bh[0] = *(const bf16x8*)(ph);                                      \
    bh[1] = *(const bf16x8*)(ph + 1024);                               \
    bh[2] = *(const bf16x8*)(ph + 2048);                               \
    bh[3] = *(const bf16x8*)(ph + 3072);                               \
    bl[0] = *(const bf16x8*)(pl);                                      \
    bl[1] = *(const bf16x8*)(pl + 1024);                               \
    bl[2] = *(const bf16x8*)(pl + 2048);                               \
    bl[3] = *(const bf16x8*)(pl + 3072);                               \
  } while (0)

  char* bufR = smem;
  char* bufM = smem + ABY;
  char* bufS = smem + 2 * ABY;

  SB;
  STAGE_A(bufR);
  SB;
  LOAD_B(bh0, bl0, 0);
  SB;
  aoff = ASTEP;
  STAGE_A(bufM);
  SB;
  LOAD_B(bh1, bl1, 4096);
  SB;
  aoff = (2 * ASTEP < amax) ? 2 * ASTEP : amax;
  boff = (2 * 4096 < bmax) ? 2 * 4096 : bmax;
  asm volatile("s_waitcnt vmcnt(%0)" ::"i"(W2N) : "memory");
  __builtin_amdgcn_s_barrier();
  SB;

#define KSTEP(BH, BL)                                                        \
  do {                                                                       \
    STAGE_A(bufS);                                                           \
    aoff = (aoff < amax) ? aoff + ASTEP : aoff;                              \
    SB;                                                                      \
    bf16x8 af[FM];                                                           \
    _Pragma("unroll") for (int m = 0; m < FM; ++m) {                         \
      const int fr = wm * FM + m;                                            \
      af[m] = *(const bf16x8*)(bufR + (fr * 64 + lane) * 16);                \
    }                                                                        \
    SB;                                                                      \
    _Pragma("unroll") for (int m = 0; m < FM; ++m) {                         \
      _Pragma("unroll") for (int n = 0; n < 4; ++n) {                        \
        acc[m][n] = __builtin_amdgcn_mfma_f32_16x16x32_bf16(af[m], BH[n],    \
                                                            acc[m][n], 0, 0, 0); \
        acc[m][n] = __builtin_amdgcn_mfma_f32_16x16x32_bf16(af[m], BL[n],    \
                                                            acc[m][n], 0, 0, 0); \
      }                                                                      \
      if constexpr (LNFOLD)                                                  \
        acc1[m] = __builtin_amdgcn_mfma_f32_16x16x32_bf16(af[m], ONES,       \
                                                          acc1[m], 0, 0, 0); \
    }                                                                        \
    SB;                                                                      \
    LOAD_B(BH, BL, boff);                                                    \
    boff = (boff < bmax) ? boff + 4096 : boff;                               \
    SB;                                                                      \
    asm volatile("s_waitcnt vmcnt(%0)" ::"i"(W2N) : "memory");               \
    __builtin_amdgcn_s_barrier();                                            \
    SB;                                                                      \
    { char* t = bufR; bufR = bufM; bufM = bufS; bufS = t; }                  \
  } while (0)

  const int ITER = KB / 2;
  for (int it = 0; it < ITER; ++it) {
    KSTEP(bh0, bl0);
    KSTEP(bh1, bl1);
  }
  asm volatile("s_waitcnt vmcnt(0) lgkmcnt(0)" ::: "memory");

#undef KSTEP
#undef LOAD_B
#undef STAGE_A

  const int row0w = row0 + wm * TM;
  const int col0w = col0 + wc * 64;
#pragma unroll
  for (int m = 0; m < FM; ++m) {
    const int rbase = row0w + m * 16 + l4 * 4;
    float iv[4], mv[4];
    if constexpr (LNFOLD) {
#pragma unroll
      for (int r = 0; r < 4; ++r) {
        const float mean = acc1[m][r] / (float)K;
        const float inv = 1.0f / sqrtf(mean * (1.f - mean) + 1e-6f);
        iv[r] = inv;
        mv[r] = mean * inv;
      }
    }
#pragma unroll
    for (int n = 0; n < 4; ++n) {
      const int c = col0w + n * 16 + l15;
      const float cc = cvec[c];
      float uu = 0.f;
      if constexpr (LNFOLD) uu = uvec[c];
#pragma unroll
      for (int r = 0; r < 4; ++r) {
        float v;
        if constexpr (LNFOLD) v = iv[r] * acc[m][n][r] - mv[r] * uu + cc;
        else v = acc[m][n][r] + cc;
        C[(size_t)(rbase + r) * N + c] = v;
      }
    }
  }
}

// W[K,N] f32 (opt. LN-scale s[k]) -> split hi/lo bf16, frag-linear.
__global__ void prep_split(const float* __restrict__ W, const float* __restrict__ s,
                           char* __restrict__ hi, char* __restrict__ lo,
                           int K, int N) {
  const int g = blockIdx.x * 256 + threadIdx.x;
  const int total = (K * N) / 8;
  if (g >= total) return;
  constexpr int UB = 256;
  const int KB = K / 32;
  const int unit = g % UB;
  const int kb = (g / UB) % KB;
  const int cb = g / (UB * KB);
  const int n = cb * 64 + ((unit >> 6) << 4) + (unit & 15);
  const int kbase = kb * 32 + ((unit >> 4) & 3) * 8;
  short h8[8], l8[8];
#pragma unroll
  for (int jj = 0; jj < 8; ++jj) {
    const int k = kbase + jj;
    float w = W[(size_t)k * N + n];
    if (s) w *= s[k];
    const unsigned short hb = f2bf_rne(w);
    const unsigned short lb = f2bf_rne(w - bf2f(hb));
    h8[jj] = (short)hb;
    l8[jj] = (short)lb;
  }
  *(bf16x8*)(hi + (size_t)g * 16) = *(const bf16x8*)h8;
  *(bf16x8*)(lo + (size_t)g * 16) = *(const bf16x8*)l8;
}

// u[n] = sum_k s[k]*W[k,n];  c[n] = sum_k b[k]*W[k,n] + bias2[n].
__global__ __launch_bounds__(256) void prep_consts(
    const float* __restrict__ W, const float* __restrict__ s,
    const float* __restrict__ b, const float* __restrict__ bias2,
    float* __restrict__ u, float* __restrict__ c, int K, int N) {
  const int n = blockIdx.x;
  const int t = threadIdx.x;
  float us = 0.f, cs = 0.f;
  for (int k = t; k < K; k += 256) {
    const float w = W[(size_t)k * N + n];
    us += s[k] * w;
    cs += b[k] * w;
  }
  __shared__ float su[256], sc[256];
  su[t] = us;
  sc[t] = cs;
  __syncthreads();
  for (int o = 128; o > 0; o >>= 1) {
    if (t < o) { su[t] += su[t + o]; sc[t] += sc[t + o]; }
    __syncthreads();
  }
  if (t == 0) { u[n] = su[0]; c[n] = sc[0] + bias2[n]; }
}

// ---------------------------------------------------------------------------
// LIF scan over T, one thread per (b,h); fp32 currents -> bf16 spikes
// and/or per-(b,h) spike counts. 32x unrolled loads.
// ---------------------------------------------------------------------------
template <int H, bool SPIKE_OUT, bool ACCUM>
__global__ void lif_scan(const float* __restrict__ xt,
                         unsigned short* __restrict__ sp,
                         float* __restrict__ tsum) {
  const int n = blockIdx.x * 64 + threadIdx.x;
  const int b = n / H, h = n % H;
  const float* p = xt + (size_t)b * T_STEPS * H + h;
  unsigned short* q = nullptr;
  if constexpr (SPIKE_OUT) q = sp + (size_t)b * T_STEPS * H + h;

  float v = 0.f, cur = 0.f, ts = 0.f;
  for (int t = 0; t < T_STEPS; t += 32) {
    float x[32];
#pragma unroll
    for (int u = 0; u < 32; ++u) x[u] = p[(size_t)u * H];
#pragma unroll
    for (int u = 0; u < 32; ++u) {
      cur = BETA_ * cur + x[u];
      v = ALPHA_ * v + cur;
      const bool sb = (v >= 1.f);
      if constexpr (SPIKE_OUT) q[(size_t)u * H] = sb ? 0x3F80 : 0;
      if constexpr (ACCUM) ts += sb ? 1.f : 0.f;
      v = sb ? 0.f : v;
    }
    p += (size_t)32 * H;
    if constexpr (SPIKE_OUT) q += (size_t)32 * H;
  }
  if constexpr (ACCUM) tsum[n] = ts;
}

__global__ void finalize(const float* __restrict__ tsum,
                         const float* __restrict__ Wc,
                         const float* __restrict__ bc,
                         float* __restrict__ out) {
  const int b = threadIdx.x;
  float s = 0.f;
#pragma unroll 8
  for (int h = 0; h < 64; ++h) s += tsum[b * 64 + h];
  const float pooled = s * (1.0f / (512.f * 64.f));
  out[2 + b] = pooled;

  float tot = pooled;
  float l0 = pooled * Wc[b * 2 + 0];
  float l1 = pooled * Wc[b * 2 + 1];
#pragma unroll
  for (int off = 32; off > 0; off >>= 1) {
    tot += __shfl_xor(tot, off);
    l0 += __shfl_xor(l0, off);
    l1 += __shfl_xor(l1, off);
  }
  if (b == 0) {
    out[0] = l0 + bc[0];
    out[1] = l1 + bc[1];
    out[66] = tot * (1.0f / 64.f);
  }
}

extern "C" void kernel_launch(void* const* d_in, const int* in_sizes, int n_in,
                              void* d_out, int out_size, void* d_ws, size_t ws_size,
                              hipStream_t stream) {
  const float* X    = (const float*)d_in[0];   // [64,512,64,16] -> [32768,1024]
  const float* W0   = (const float*)d_in[1];   // [1024,256]
  const float* b0   = (const float*)d_in[2];
  const float* W1   = (const float*)d_in[3];   // [256,128]
  const float* b1   = (const float*)d_in[4];
  const float* W2   = (const float*)d_in[5];   // [128,64]
  const float* b2   = (const float*)d_in[6];
  const float* ln1s = (const float*)d_in[7];
  const float* ln1b = (const float*)d_in[8];
  const float* ln2s = (const float*)d_in[9];
  const float* ln2b = (const float*)d_in[10];
  const float* Wc   = (const float*)d_in[11];  // [64,2]
  const float* bc   = (const float*)d_in[12];
  float* out = (float*)d_out;

  char* w = (char*)d_ws;
  float* buf0 = (float*)w;                       // [32768,256] f32 = 33554432 B
  float* buf1 = (float*)w;                       // alias: buf0 dead after scan0
  float* buf2 = (float*)(w + 16777216);          // [32768,64] f32
  size_t off = 33554432;
  unsigned short* sp0 = (unsigned short*)(w + off); off += 16777216;  // bf16
  unsigned short* sp1 = (unsigned short*)(w + off); off += 8388608;   // bf16
  char* bq0 = w + off; off += 524288;            // W0 two-level i8 frag-linear
  char* hi1 = w + off; off += 65536;
  char* lo1 = w + off; off += 65536;
  char* hi2 = w + off; off += 16384;
  char* lo2 = w + off; off += 16384;
  float* u1 = (float*)(w + off); off += 512;
  float* c1 = (float*)(w + off); off += 512;
  float* u2 = (float*)(w + off); off += 256;
  float* c2 = (float*)(w + off); off += 256;
  unsigned int* slots = (unsigned int*)(w + off); off += 256;
  float* tsum = (float*)(w + off); off += 16384;

  const int M = 32768;

  // --- weight prep: i8 quant for W0; bf16 hi/lo split for W1/W2 ---
  zero_slots<<<1, 64, 0, stream>>>(slots);
  prep_maxabs<<<64, 256, 0, stream>>>(W0, slots, 1024 * 256);
  prep_quant<<<128, 256, 0, stream>>>(W0, slots, bq0, 1024, 256);
  prep_split<<<16, 256, 0, stream>>>(W1, ln1s, hi1, lo1, 256, 128);
  prep_split<<<4, 256, 0, stream>>>(W2, ln2s, hi2, lo2, 128, 64);
  prep_consts<<<128, 256, 0, stream>>>(W1, ln1s, ln1b, b1, u1, c1, 256, 128);
  prep_consts<<<64, 256, 0, stream>>>(W2, ln2s, ln2b, b2, u2, c2, 128, 64);

  // --- layer 0: min-traffic i8 GEMM (R18). BM=128, BN=256, grid 256. ---
  gemm_i8w<<<M / 128, 512, 0, stream>>>(X, bq0, slots, b0, buf0, 256, 1024);
  lif_scan<256, true, false><<<(BATCH * 256) / 64, 64, 0, stream>>>(buf0, sp0, nullptr);

  // --- layer 1: R15 best (bf16 hi/lo deep2, LN folded). ---
  gemm_deep2<2, 2, 32, true><<<dim3(1, M / 64), 256, 0, stream>>>(
      sp0, hi1, lo1, u1, c1, buf1, 128, 256);
  lif_scan<128, true, false><<<(BATCH * 128) / 64, 64, 0, stream>>>(buf1, sp1, nullptr);

  // --- layer 2: R15 best (BM=128). ---
  gemm_deep2<4, 1, 32, true><<<dim3(1, M / 128), 256, 0, stream>>>(
      sp1, hi2, lo2, u2, c2, buf2, 64, 128);
  lif_scan<64, false, true><<<(BATCH * 64) / 64, 64, 0, stream>>>(buf2, nullptr, tsum);

  finalize<<<1, 64, 0, stream>>>(tsum, Wc, bc, out);
}

// Round 20
// 125.529 us; speedup vs baseline: 1.2523x; 1.0802x over previous
//
#include <hip/hip_runtime.h>

#define T_STEPS 512
#define BATCH 64

// fp32 casts of np.exp(-1/20), np.exp(-1/5)
__device__ constexpr float ALPHA_ = 0.95122942450071400910f;
__device__ constexpr float BETA_  = 0.81873075307798185867f;

typedef __attribute__((ext_vector_type(8))) short bf16x8;
typedef __attribute__((ext_vector_type(4))) float f32x4;

__device__ inline unsigned short f2bf_rne(float f) {
  union { float f; unsigned int u; } v{f};
  const unsigned int u = v.u;
  return (unsigned short)((u + 0x7FFFu + ((u >> 16) & 1u)) >> 16);
}
__device__ inline float bf2f(unsigned short h) {
  union { unsigned int u; float f; } v{(unsigned int)h << 16};
  return v.f;
}

__device__ inline void gload16(const void* g, void* l) {
  __builtin_amdgcn_global_load_lds(
      (const __attribute__((address_space(1))) unsigned int*)g,
      (__attribute__((address_space(3))) unsigned int*)l, 16, 0, 0);
}

// pack trunc-bf16(first) | trunc-bf16(second)<<16  (exact for spike 0/1)
__device__ inline unsigned int pkbf(float first, float second) {
#if __has_builtin(__builtin_amdgcn_perm)
  return __builtin_amdgcn_perm(__float_as_uint(second), __float_as_uint(first),
                               0x07060302u);
#else
  return (__float_as_uint(first) >> 16) | (__float_as_uint(second) & 0xFFFF0000u);
#endif
}

// 8 fp32 (lo = k0..3, hi = k4..7) -> MFMA bf16x8 fragment word order
__device__ inline bf16x8 cvt_frag(const f32x4 lo, const f32x4 hi) {
  union { unsigned int w[4]; bf16x8 v; } u;
  u.w[0] = pkbf(lo.x, lo.y);
  u.w[1] = pkbf(lo.z, lo.w);
  u.w[2] = pkbf(hi.x, hi.y);
  u.w[3] = pkbf(hi.z, hi.w);
  return u.v;
}

#define SB __builtin_amdgcn_sched_barrier(0)

// ---------------------------------------------------------------------------
// R15 production GEMM (best measured total: 126.7 us). Deep-pipelined,
// depth-2, triple-buffered A LDS via gload_lds, B hi/lo in compiler-managed
// ping-pong regs, counted vmcnt(AIP+16) before the raw s_barrier.
// COAL (A_F32): contiguous 8-rows x 128B staging, chunk-XOR swizzle on
// source AND ds_read (2-way banks, free).
// LNFOLD: rowsum via ones-MFMA; epilogue inv[r]*acc - mi[r]*u[c] + c[c].
// ---------------------------------------------------------------------------
template <int WM, int WC, int TM, bool A_F32, bool LNFOLD, bool COAL>
__global__ __launch_bounds__(256) void gemm_deep2(
    const void* __restrict__ Av, const char* __restrict__ Bhi,
    const char* __restrict__ Blo, const float* __restrict__ uvec,
    const float* __restrict__ cvec, float* __restrict__ C, int N, int K) {
  constexpr int BM = WM * TM;
  constexpr int FM = TM / 16;                      // m-frags per wave
  constexpr int ABY = A_F32 ? BM * 128 : BM * 64;  // A bytes per K-step
  constexpr int AIP = ABY / 4096;                  // A gloads per thread
  constexpr int ASTEP = A_F32 ? 128 : 64;          // A source bytes per kb
  constexpr int W2N = AIP + 16;                    // completes A(next)
  __shared__ char smem[3 * ABY];

  const int tid = threadIdx.x;
  const int lane = tid & 63;
  const int wave = tid >> 6;
  const int wm = wave / WC, wc = wave % WC;
  const int l15 = lane & 15, l4 = lane >> 4;
  const int row0 = blockIdx.y * BM;
  const int col0 = blockIdx.x * (WC * 64);
  const int KB = K / 32;

  const char* Ab = (const char*)Av;

  const char* a_src[AIP];
#pragma unroll
  for (int i = 0; i < AIP; ++i) {
    const int unit = i * 256 + tid;
    if constexpr (A_F32 && COAL) {
      const int r = unit >> 3, c = unit & 7;   // 8 rows x 128B, chunk-swizzled
      a_src[i] = Ab + ((size_t)(row0 + r) * K) * 4 + ((c * 16) ^ ((r & 7) << 4));
    } else if constexpr (A_F32) {
      const int fr = unit >> 7, h = (unit >> 6) & 1, ln = unit & 63;
      a_src[i] = Ab + ((size_t)(row0 + fr * 16 + (ln & 15)) * K + ((ln >> 4) * 8)) * 4 + h * 16;
    } else {
      const int r = ((unit >> 6) << 4) | (unit & 15);
      const int j = (unit >> 4) & 3;
      a_src[i] = Ab + ((size_t)(row0 + r) * K + j * 8) * 2;
    }
  }
  const char* bh_base = Bhi + (size_t)(blockIdx.x * WC + wc) * KB * 4096 + (size_t)lane * 16;
  const char* bl_base = Blo + (size_t)(blockIdx.x * WC + wc) * KB * 4096 + (size_t)lane * 16;

  int aoff = 0, boff = 0;
  const int amax = (KB - 1) * ASTEP;
  const int bmax = (KB - 1) * 4096;

  f32x4 acc[FM][4] = {};
  f32x4 acc1[FM] = {};
  const bf16x8 ONES = {0x3F80, 0x3F80, 0x3F80, 0x3F80,
                       0x3F80, 0x3F80, 0x3F80, 0x3F80};
  bf16x8 bh0[4], bl0[4], bh1[4], bl1[4];

#define STAGE_A(buf)                                                   \
  do {                                                                 \
    _Pragma("unroll") for (int i = 0; i < AIP; ++i)                    \
        gload16(a_src[i] + aoff, (buf) + (i * 256 + tid) * 16);        \
  } while (0)

#define LOAD_B(bh, bl, off_)                                           \
  do {                                                                 \
    const char* ph = bh_base + (off_);                                 \
    const char* pl = bl_base + (off_);                                 \
    bh[0] = *(const bf16x8*)(ph);                                      \
    bh[1] = *(const bf16x8*)(ph + 1024);                               \
    bh[2] = *(const bf16x8*)(ph + 2048);                               \
    bh[3] = *(const bf16x8*)(ph + 3072);                               \
    bl[0] = *(const bf16x8*)(pl);                                      \
    bl[1] = *(const bf16x8*)(pl + 1024);                               \
    bl[2] = *(const bf16x8*)(pl + 2048);                               \
    bl[3] = *(const bf16x8*)(pl + 3072);                               \
  } while (0)

  char* bufR = smem;
  char* bufM = smem + ABY;
  char* bufS = smem + 2 * ABY;

  // ---- prologue ----
  SB;
  STAGE_A(bufR);                      // A(0)
  SB;
  LOAD_B(bh0, bl0, 0);                // B(0)
  SB;
  aoff = ASTEP;
  STAGE_A(bufM);                      // A(1)
  SB;
  LOAD_B(bh1, bl1, 4096);             // B(1)
  SB;
  aoff = (2 * ASTEP < amax) ? 2 * ASTEP : amax;
  boff = (2 * 4096 < bmax) ? 2 * 4096 : bmax;
  asm volatile("s_waitcnt vmcnt(%0)" ::"i"(W2N) : "memory");  // A(0) landed
  __builtin_amdgcn_s_barrier();
  SB;

#define KSTEP(BH, BL)                                                        \
  do {                                                                       \
    STAGE_A(bufS); /* A(kb+2) */                                             \
    aoff = (aoff < amax) ? aoff + ASTEP : aoff;                              \
    SB;                                                                      \
    bf16x8 af[FM];                                                           \
    _Pragma("unroll") for (int m = 0; m < FM; ++m) {                         \
      if constexpr (A_F32 && COAL) {                                         \
        const int rr = wm * TM + m * 16 + l15;                               \
        const int sw = (rr & 7) << 4;                                        \
        const f32x4 lo = *(const f32x4*)(bufR + rr * 128 + ((l4 * 32) ^ sw)); \
        const f32x4 hi = *(const f32x4*)(bufR + rr * 128 + ((l4 * 32 + 16) ^ sw)); \
        af[m] = cvt_frag(lo, hi);                                            \
      } else if constexpr (A_F32) {                                          \
        const int fr = wm * FM + m;                                          \
        const f32x4 lo = *(const f32x4*)(bufR + ((fr * 2 + 0) * 64 + lane) * 16); \
        const f32x4 hi = *(const f32x4*)(bufR + ((fr * 2 + 1) * 64 + lane) * 16); \
        af[m] = cvt_frag(lo, hi);                                            \
      } else {                                                               \
        const int fr = wm * FM + m;                                          \
        af[m] = *(const bf16x8*)(bufR + (fr * 64 + lane) * 16);              \
      }                                                                      \
    }                                                                        \
    SB;                                                                      \
    _Pragma("unroll") for (int m = 0; m < FM; ++m) {                         \
      _Pragma("unroll") for (int n = 0; n < 4; ++n) {                        \
        acc[m][n] = __builtin_amdgcn_mfma_f32_16x16x32_bf16(af[m], BH[n],    \
                                                            acc[m][n], 0, 0, 0); \
        acc[m][n] = __builtin_amdgcn_mfma_f32_16x16x32_bf16(af[m], BL[n],    \
                                                            acc[m][n], 0, 0, 0); \
      }                                                                      \
      if constexpr (LNFOLD)                                                  \
        acc1[m] = __builtin_amdgcn_mfma_f32_16x16x32_bf16(af[m], ONES,       \
                                                          acc1[m], 0, 0, 0); \
    }                                                                        \
    SB;                                                                      \
    LOAD_B(BH, BL, boff); /* B(kb+2) */                                      \
    boff = (boff < bmax) ? boff + 4096 : boff;                               \
    SB;                                                                      \
    asm volatile("s_waitcnt vmcnt(%0)" ::"i"(W2N) : "memory");               \
    __builtin_amdgcn_s_barrier();                                            \
    SB;                                                                      \
    { char* t = bufR; bufR = bufM; bufM = bufS; bufS = t; }                  \
  } while (0)

  const int ITER = KB / 2;
  for (int it = 0; it < ITER; ++it) {
    KSTEP(bh0, bl0);
    KSTEP(bh1, bl1);
  }
  asm volatile("s_waitcnt vmcnt(0) lgkmcnt(0)" ::: "memory");

#undef KSTEP
#undef LOAD_B
#undef STAGE_A

  const int row0w = row0 + wm * TM;
  const int col0w = col0 + wc * 64;
#pragma unroll
  for (int m = 0; m < FM; ++m) {
    const int rbase = row0w + m * 16 + l4 * 4;
    float iv[4], mv[4];
    if constexpr (LNFOLD) {
#pragma unroll
      for (int r = 0; r < 4; ++r) {
        const float mean = acc1[m][r] / (float)K;
        const float inv = 1.0f / sqrtf(mean * (1.f - mean) + 1e-6f);
        iv[r] = inv;
        mv[r] = mean * inv;
      }
    }
#pragma unroll
    for (int n = 0; n < 4; ++n) {
      const int c = col0w + n * 16 + l15;
      const float cc = cvec[c];
      float uu = 0.f;
      if constexpr (LNFOLD) uu = uvec[c];
#pragma unroll
      for (int r = 0; r < 4; ++r) {
        float v;
        if constexpr (LNFOLD) v = iv[r] * acc[m][n][r] - mv[r] * uu + cc;
        else v = acc[m][n][r] + cc;
        C[(size_t)(rbase + r) * N + c] = v;
      }
    }
  }
}

// ---------------------------------------------------------------------------
// Prep: W[K,N] f32 (optionally scaled by s[k]) -> split hi/lo bf16 in the
// fragment-linear (64-col-block) global layout consumed by the GEMMs.
// ---------------------------------------------------------------------------
__global__ void prep_split(const float* __restrict__ W, const float* __restrict__ s,
                           char* __restrict__ hi, char* __restrict__ lo,
                           int K, int N) {
  const int g = blockIdx.x * 256 + threadIdx.x;
  const int total = (K * N) / 8;
  if (g >= total) return;
  constexpr int UB = 256;
  const int KB = K / 32;
  const int unit = g % UB;
  const int kb = (g / UB) % KB;
  const int cb = g / (UB * KB);
  const int n = cb * 64 + ((unit >> 6) << 4) + (unit & 15);
  const int kbase = kb * 32 + ((unit >> 4) & 3) * 8;
  short h8[8], l8[8];
#pragma unroll
  for (int jj = 0; jj < 8; ++jj) {
    const int k = kbase + jj;
    float w = W[(size_t)k * N + n];
    if (s) w *= s[k];
    const unsigned short hb = f2bf_rne(w);
    const unsigned short lb = f2bf_rne(w - bf2f(hb));
    h8[jj] = (short)hb;
    l8[jj] = (short)lb;
  }
  *(bf16x8*)(hi + (size_t)g * 16) = *(const bf16x8*)h8;
  *(bf16x8*)(lo + (size_t)g * 16) = *(const bf16x8*)l8;
}

// u[n] = sum_k s[k]*W[k,n];  c[n] = sum_k b[k]*W[k,n] + bias2[n]. Block per n.
__global__ __launch_bounds__(256) void prep_consts(
    const float* __restrict__ W, const float* __restrict__ s,
    const float* __restrict__ b, const float* __restrict__ bias2,
    float* __restrict__ u, float* __restrict__ c, int K, int N) {
  const int n = blockIdx.x;
  const int t = threadIdx.x;
  float us = 0.f, cs = 0.f;
  for (int k = t; k < K; k += 256) {
    const float w = W[(size_t)k * N + n];
    us += s[k] * w;
    cs += b[k] * w;
  }
  __shared__ float su[256], sc[256];
  su[t] = us;
  sc[t] = cs;
  __syncthreads();
  for (int o = 128; o > 0; o >>= 1) {
    if (t < o) { su[t] += su[t + o]; sc[t] += sc[t + o]; }
    __syncthreads();
  }
  if (t == 0) { u[n] = su[0]; c[n] = sc[0] + bias2[n]; }
}

// ---------------------------------------------------------------------------
// LIF scan over T, one thread per (b,h); fp32 currents -> bf16 spikes and/or
// per-(b,h) spike counts. UNROLL=128 (4 stall windows instead of 16; scans
// run 1 wave/CU so 128+ VGPRs are free — latency, not occupancy, is the wall).
// ---------------------------------------------------------------------------
template <int H, bool SPIKE_OUT, bool ACCUM>
__global__ void lif_scan(const float* __restrict__ xt,
                         unsigned short* __restrict__ sp,
                         float* __restrict__ tsum) {
  const int n = blockIdx.x * 64 + threadIdx.x;
  const int b = n / H, h = n % H;
  const float* p = xt + (size_t)b * T_STEPS * H + h;
  unsigned short* q = nullptr;
  if constexpr (SPIKE_OUT) q = sp + (size_t)b * T_STEPS * H + h;

  float v = 0.f, cur = 0.f, ts = 0.f;
  for (int t = 0; t < T_STEPS; t += 128) {
    float x[128];
#pragma unroll
    for (int u = 0; u < 128; ++u) x[u] = p[(size_t)u * H];
#pragma unroll
    for (int u = 0; u < 128; ++u) {
      cur = BETA_ * cur + x[u];
      v = ALPHA_ * v + cur;
      const bool sb = (v >= 1.f);
      if constexpr (SPIKE_OUT) q[(size_t)u * H] = sb ? 0x3F80 : 0;
      if constexpr (ACCUM) ts += sb ? 1.f : 0.f;
      v = sb ? 0.f : v;
    }
    p += (size_t)128 * H;
    if constexpr (SPIKE_OUT) q += (size_t)128 * H;
  }
  if constexpr (ACCUM) tsum[n] = ts;
}

__global__ void finalize(const float* __restrict__ tsum,
                         const float* __restrict__ Wc,
                         const float* __restrict__ bc,
                         float* __restrict__ out) {
  const int b = threadIdx.x;  // 64 threads, one wave
  float s = 0.f;
#pragma unroll 8
  for (int h = 0; h < 64; ++h) s += tsum[b * 64 + h];
  const float pooled = s * (1.0f / (512.f * 64.f));
  out[2 + b] = pooled;

  float tot = pooled;
  float l0 = pooled * Wc[b * 2 + 0];
  float l1 = pooled * Wc[b * 2 + 1];
#pragma unroll
  for (int off = 32; off > 0; off >>= 1) {
    tot += __shfl_xor(tot, off);
    l0 += __shfl_xor(l0, off);
    l1 += __shfl_xor(l1, off);
  }
  if (b == 0) {
    out[0] = l0 + bc[0];
    out[1] = l1 + bc[1];
    out[66] = tot * (1.0f / 64.f);
  }
}

extern "C" void kernel_launch(void* const* d_in, const int* in_sizes, int n_in,
                              void* d_out, int out_size, void* d_ws, size_t ws_size,
                              hipStream_t stream) {
  const float* X    = (const float*)d_in[0];   // [64,512,64,16] -> [32768,1024]
  const float* W0   = (const float*)d_in[1];   // [1024,256]
  const float* b0   = (const float*)d_in[2];
  const float* W1   = (const float*)d_in[3];   // [256,128]
  const float* b1   = (const float*)d_in[4];
  const float* W2   = (const float*)d_in[5];   // [128,64]
  const float* b2   = (const float*)d_in[6];
  const float* ln1s = (const float*)d_in[7];
  const float* ln1b = (const float*)d_in[8];
  const float* ln2s = (const float*)d_in[9];
  const float* ln2b = (const float*)d_in[10];
  const float* Wc   = (const float*)d_in[11];  // [64,2]
  const float* bc   = (const float*)d_in[12];
  float* out = (float*)d_out;

  char* w = (char*)d_ws;
  float* buf0 = (float*)w;                       // [32768,256] f32 = 33554432 B
  float* buf1 = (float*)w;                       // alias: buf0 dead after scan0
  float* buf2 = (float*)(w + 16777216);          // [32768,64] f32, after buf1
  size_t off = 33554432;
  unsigned short* sp0 = (unsigned short*)(w + off); off += 16777216;  // bf16
  unsigned short* sp1 = (unsigned short*)(w + off); off += 8388608;   // bf16
  char* hi0 = w + off; off += 524288;
  char* lo0 = w + off; off += 524288;
  char* hi1 = w + off; off += 65536;
  char* lo1 = w + off; off += 65536;
  char* hi2 = w + off; off += 16384;
  char* lo2 = w + off; off += 16384;
  float* u1 = (float*)(w + off); off += 512;
  float* c1 = (float*)(w + off); off += 512;
  float* u2 = (float*)(w + off); off += 256;
  float* c2 = (float*)(w + off); off += 256;
  float* tsum = (float*)(w + off); off += 16384;

  const int M = 32768;

  // --- weight prep (frag-linear 64-col-block split hi/lo + LN-fold consts) ---
  prep_split<<<128, 256, 0, stream>>>(W0, nullptr, hi0, lo0, 1024, 256);
  prep_split<<<16, 256, 0, stream>>>(W1, ln1s, hi1, lo1, 256, 128);
  prep_split<<<4, 256, 0, stream>>>(W2, ln2s, hi2, lo2, 128, 64);
  prep_consts<<<128, 256, 0, stream>>>(W1, ln1s, ln1b, b1, u1, c1, 256, 128);
  prep_consts<<<64, 256, 0, stream>>>(W2, ln2s, ln2b, b2, u2, c2, 128, 64);

  // --- layer 0: R15 best (deep2 + COAL). BM=64, BN=256, grid (1,512). ---
  gemm_deep2<1, 4, 64, true, false, true><<<dim3(1, M / 64), 256, 0, stream>>>(
      X, hi0, lo0, nullptr, b0, buf0, 256, 1024);
  lif_scan<256, true, false><<<(BATCH * 256) / 64, 64, 0, stream>>>(buf0, sp0, nullptr);

  // --- layer 1: R15 best (LN folded). BM=64, BN=128, grid (1,512). ---
  gemm_deep2<2, 2, 32, false, true, false><<<dim3(1, M / 64), 256, 0, stream>>>(
      sp0, hi1, lo1, u1, c1, buf1, 128, 256);
  lif_scan<128, true, false><<<(BATCH * 128) / 64, 64, 0, stream>>>(buf1, sp1, nullptr);

  // --- layer 2: R15 best. BM=128, BN=64, grid (1,256). ---
  gemm_deep2<4, 1, 32, false, true, false><<<dim3(1, M / 128), 256, 0, stream>>>(
      sp1, hi2, lo2, u2, c2, buf2, 64, 128);
  lif_scan<64, false, true><<<(BATCH * 64) / 64, 64, 0, stream>>>(buf2, nullptr, tsum);

  finalize<<<1, 64, 0, stream>>>(tsum, Wc, bc, out);
}